// Round 5
// baseline (578.219 us; speedup 1.0000x reference)
//
#include <hip/hip_runtime.h>

// Problem constants (reference: x [64,256,64,64] fp32, keep_num=2048)
#define BB 64
#define CC 256
#define NN 4096          // 64*64 tokens
#define KKEEP 2048
#define NCHUNK 8         // channel chunks
#define CCHUNK 32        // channels per chunk (8 x 32 = 256)

// ---------------------------------------------------------------------------
// MEASUREMENT ROUND: source is byte-identical to R4; the only change is that
// pool_kernel is launched 4x (it is a pure function of x and M, so repeats
// write identical bytes).  dur_us - 420.86 = 3 x k3 + ~6 us launch gaps.
// This localizes the ~90 us of unexplained kernel time (168 us inferred vs
// ~75 us roofline) to k3 vs (k1|k2) without any harness-cost assumption.
// ---------------------------------------------------------------------------

__global__ __launch_bounds__(256, 8) void score_partial_kernel(
    const float* __restrict__ x, float* __restrict__ P) {
    const int b  = blockIdx.x >> 2;
    const int ng = blockIdx.x & 3;
    const int cy = blockIdx.y;
    const int n0 = ng * 1024 + threadIdx.x * 4;
    const float* xb = x + (size_t)(b * CC + cy * CCHUNK) * NN + n0;
    float4 acc = make_float4(0.f, 0.f, 0.f, 0.f);
    #pragma unroll 8
    for (int c = 0; c < CCHUNK; ++c) {
        const float4 v = *(const float4*)(xb + (size_t)c * NN);
        acc.x += fabsf(v.x); acc.y += fabsf(v.y);
        acc.z += fabsf(v.z); acc.w += fabsf(v.w);
    }
    *(float4*)(P + (size_t)(cy * BB + b) * NN + n0) = acc;
}

__global__ __launch_bounds__(256) void select_kernel(
    const float* __restrict__ P, float* __restrict__ M) {
    const int b = blockIdx.x;
    const int t = threadIdx.x;
    __shared__ unsigned wred[2][4];
    __shared__ unsigned cnts[256];

    const int base = t * 16;
    unsigned su[16];
    #pragma unroll
    for (int j = 0; j < 16; j += 4) {
        float4 s = make_float4(0.f, 0.f, 0.f, 0.f);
        #pragma unroll
        for (int cy = 0; cy < NCHUNK; ++cy) {
            const float4 a = *(const float4*)(P + (size_t)(cy * BB + b) * NN + base + j);
            s.x += a.x; s.y += a.y; s.z += a.z; s.w += a.w;
        }
        su[j + 0] = __float_as_uint(s.x);
        su[j + 1] = __float_as_uint(s.y);
        su[j + 2] = __float_as_uint(s.z);
        su[j + 3] = __float_as_uint(s.w);
    }

    int slot = 0;
    auto reduce_add = [&](unsigned v) -> unsigned {
        #pragma unroll
        for (int off = 32; off; off >>= 1) v += __shfl_down(v, off, 64);
        if ((t & 63) == 0) wred[slot][t >> 6] = v;
        __syncthreads();
        unsigned tot = wred[slot][0] + wred[slot][1] + wred[slot][2] + wred[slot][3];
        slot ^= 1;
        return tot;
    };
    auto count_ge = [&](unsigned thr) -> unsigned {
        unsigned c = 0;
        #pragma unroll
        for (int j = 0; j < 16; ++j) c += (su[j] >= thr) ? 1u : 0u;
        return reduce_add(c);
    };

    unsigned lmax = 0;
    #pragma unroll
    for (int j = 0; j < 16; ++j) lmax = (su[j] > lmax) ? su[j] : lmax;
    {
        unsigned v = lmax;
        #pragma unroll
        for (int off = 32; off; off >>= 1) {
            unsigned w = __shfl_down(v, off, 64);
            v = (w > v) ? w : v;
        }
        if ((t & 63) == 0) wred[slot][t >> 6] = v;
        __syncthreads();
        unsigned m01 = (wred[slot][0] > wred[slot][1]) ? wred[slot][0] : wred[slot][1];
        unsigned m23 = (wred[slot][2] > wred[slot][3]) ? wred[slot][2] : wred[slot][3];
        lmax = (m01 > m23) ? m01 : m23;
        slot ^= 1;
    }
    const unsigned mx = lmax;

    float* mb = M + (size_t)b * NN + base;

    unsigned T = 0;
    bool done = false;
    for (int bit = 31; bit >= 0; --bit) {
        const unsigned cand = T | (1u << bit);
        if (cand > mx) continue;               // free reject: no value >= cand
        const unsigned c = count_ge(cand);
        if (c >= KKEEP) {
            T = cand;
            if (c == KKEEP) { done = true; break; }  // set uniquely determined
        }
    }

    if (done) {
        #pragma unroll
        for (int j = 0; j < 16; ++j) mb[j] = (su[j] >= T) ? 1.0f : 0.0f;
        return;
    }

    const unsigned cnt_gt = count_ge(T + 1u);
    const unsigned need_eq = KKEEP - cnt_gt;

    unsigned local_eq = 0;
    #pragma unroll
    for (int j = 0; j < 16; ++j) local_eq += (su[j] == T) ? 1u : 0u;
    cnts[t] = local_eq;
    __syncthreads();
    unsigned prefix = 0;
    for (int p = 0; p < t; ++p) prefix += cnts[p];

    unsigned run = prefix;
    #pragma unroll
    for (int j = 0; j < 16; ++j) {
        bool sel;
        if (su[j] > T)       sel = true;
        else if (su[j] == T) { sel = (run < need_eq); ++run; }
        else                 sel = false;
        mb[j] = sel ? 1.0f : 0.0f;
    }
}

__global__ __launch_bounds__(256) void pool_kernel(
    const float* __restrict__ x, const float* __restrict__ M,
    float* __restrict__ out) {
    const int wave = threadIdx.x >> 6;
    const int lane = threadIdx.x & 63;
    const int u    = (blockIdx.x << 2) | wave;   // 0..4095 units of 4 rows
    const int inv  = 4095 - u;                   // reverse k1 read-time order
    const int cyk  = inv >> 9;                   // k1 chunk (outer in time), 0..7
    const int rem  = inv & 511;
    const int bk   = rem >> 3;                   // k1 batch (inner in time)
    const int cb   = rem & 7;                    // 4-channel group within chunk
    const int row0 = bk * CC + cyk * CCHUNK + cb * 4;
    const float* xr = x + (size_t)row0 * NN;
    const float* mr = M + (size_t)bk * NN;
    float a0 = 0.f, a1 = 0.f, a2 = 0.f, a3 = 0.f;
    #pragma unroll 4
    for (int j = 0; j < 16; ++j) {
        const int n = j * 256 + lane * 4;
        const float4 m  = *(const float4*)(mr + n);   // shared by 4 rows
        const float4 v0 = *(const float4*)(xr + n);
        const float4 v1 = *(const float4*)(xr + (size_t)NN + n);
        const float4 v2 = *(const float4*)(xr + (size_t)2 * NN + n);
        const float4 v3 = *(const float4*)(xr + (size_t)3 * NN + n);
        a0 += v0.x * m.x + v0.y * m.y + v0.z * m.z + v0.w * m.w;
        a1 += v1.x * m.x + v1.y * m.y + v1.z * m.z + v1.w * m.w;
        a2 += v2.x * m.x + v2.y * m.y + v2.z * m.z + v2.w * m.w;
        a3 += v3.x * m.x + v3.y * m.y + v3.z * m.z + v3.w * m.w;
    }
    #pragma unroll
    for (int off = 32; off; off >>= 1) {
        a0 += __shfl_down(a0, off, 64);
        a1 += __shfl_down(a1, off, 64);
        a2 += __shfl_down(a2, off, 64);
        a3 += __shfl_down(a3, off, 64);
    }
    if (lane == 0) {
        const float s = 1.0f / 2048.0f;
        *(float4*)(out + row0) = make_float4(a0 * s, a1 * s, a2 * s, a3 * s);
    }
}

extern "C" void kernel_launch(void* const* d_in, const int* in_sizes, int n_in,
                              void* d_out, int out_size, void* d_ws, size_t ws_size,
                              hipStream_t stream) {
    const float* x = (const float*)d_in[0];
    float* out = (float*)d_out;
    float* P = (float*)d_ws;
    float* M = P + (size_t)NCHUNK * BB * NN;

    score_partial_kernel<<<dim3(BB * 4, NCHUNK), 256, 0, stream>>>(x, P);
    select_kernel<<<BB, 256, 0, stream>>>(P, M);
    // k3 launched 4x: pure function of (x, M) -> identical bytes each time.
    // dur_us - 420.86 (R4 baseline) = 3*k3 + ~6 us of launch gaps.
    pool_kernel<<<(BB * CC) / 16, 256, 0, stream>>>(x, M, out);
    pool_kernel<<<(BB * CC) / 16, 256, 0, stream>>>(x, M, out);
    pool_kernel<<<(BB * CC) / 16, 256, 0, stream>>>(x, M, out);
    pool_kernel<<<(BB * CC) / 16, 256, 0, stream>>>(x, M, out);
}

// Round 6
// 522.060 us; speedup vs baseline: 1.1076x; 1.1076x over previous
//
#include <hip/hip_runtime.h>

// Problem constants (reference: x [64,256,64,64] fp32, keep_num=2048)
#define BB 64
#define CC 256
#define NN 4096          // 64*64 tokens
#define KKEEP 2048
#define NCHUNK 8         // channel chunks
#define CCHUNK 32        // channels per chunk (8 x 32 = 256)

// ---------------------------------------------------------------------------
// MEASUREMENT ROUND 2: source byte-identical to R4 except score_partial_kernel
// is launched 3x (pure function of x -> identical P bytes each time).
// R5 established k3 + gap = 52.5 us.  This round: dur - 420.86 = 2 x (k1+gap).
// Cold-cache validity: k1 reads x forward; forward re-read of a just-streamed
// 256MB array through the 256MB LRU L3 gets ~0% hits, so every replay is
// equally HBM-cold, and k3's tail-resident L3 view is unchanged.
// ---------------------------------------------------------------------------

__global__ __launch_bounds__(256, 8) void score_partial_kernel(
    const float* __restrict__ x, float* __restrict__ P) {
    const int b  = blockIdx.x >> 2;
    const int ng = blockIdx.x & 3;
    const int cy = blockIdx.y;
    const int n0 = ng * 1024 + threadIdx.x * 4;
    const float* xb = x + (size_t)(b * CC + cy * CCHUNK) * NN + n0;
    float4 acc = make_float4(0.f, 0.f, 0.f, 0.f);
    #pragma unroll 8
    for (int c = 0; c < CCHUNK; ++c) {
        const float4 v = *(const float4*)(xb + (size_t)c * NN);
        acc.x += fabsf(v.x); acc.y += fabsf(v.y);
        acc.z += fabsf(v.z); acc.w += fabsf(v.w);
    }
    *(float4*)(P + (size_t)(cy * BB + b) * NN + n0) = acc;
}

__global__ __launch_bounds__(256) void select_kernel(
    const float* __restrict__ P, float* __restrict__ M) {
    const int b = blockIdx.x;
    const int t = threadIdx.x;
    __shared__ unsigned wred[2][4];
    __shared__ unsigned cnts[256];

    const int base = t * 16;
    unsigned su[16];
    #pragma unroll
    for (int j = 0; j < 16; j += 4) {
        float4 s = make_float4(0.f, 0.f, 0.f, 0.f);
        #pragma unroll
        for (int cy = 0; cy < NCHUNK; ++cy) {
            const float4 a = *(const float4*)(P + (size_t)(cy * BB + b) * NN + base + j);
            s.x += a.x; s.y += a.y; s.z += a.z; s.w += a.w;
        }
        su[j + 0] = __float_as_uint(s.x);
        su[j + 1] = __float_as_uint(s.y);
        su[j + 2] = __float_as_uint(s.z);
        su[j + 3] = __float_as_uint(s.w);
    }

    int slot = 0;
    auto reduce_add = [&](unsigned v) -> unsigned {
        #pragma unroll
        for (int off = 32; off; off >>= 1) v += __shfl_down(v, off, 64);
        if ((t & 63) == 0) wred[slot][t >> 6] = v;
        __syncthreads();
        unsigned tot = wred[slot][0] + wred[slot][1] + wred[slot][2] + wred[slot][3];
        slot ^= 1;
        return tot;
    };
    auto count_ge = [&](unsigned thr) -> unsigned {
        unsigned c = 0;
        #pragma unroll
        for (int j = 0; j < 16; ++j) c += (su[j] >= thr) ? 1u : 0u;
        return reduce_add(c);
    };

    unsigned lmax = 0;
    #pragma unroll
    for (int j = 0; j < 16; ++j) lmax = (su[j] > lmax) ? su[j] : lmax;
    {
        unsigned v = lmax;
        #pragma unroll
        for (int off = 32; off; off >>= 1) {
            unsigned w = __shfl_down(v, off, 64);
            v = (w > v) ? w : v;
        }
        if ((t & 63) == 0) wred[slot][t >> 6] = v;
        __syncthreads();
        unsigned m01 = (wred[slot][0] > wred[slot][1]) ? wred[slot][0] : wred[slot][1];
        unsigned m23 = (wred[slot][2] > wred[slot][3]) ? wred[slot][2] : wred[slot][3];
        lmax = (m01 > m23) ? m01 : m23;
        slot ^= 1;
    }
    const unsigned mx = lmax;

    float* mb = M + (size_t)b * NN + base;

    unsigned T = 0;
    bool done = false;
    for (int bit = 31; bit >= 0; --bit) {
        const unsigned cand = T | (1u << bit);
        if (cand > mx) continue;               // free reject: no value >= cand
        const unsigned c = count_ge(cand);
        if (c >= KKEEP) {
            T = cand;
            if (c == KKEEP) { done = true; break; }  // set uniquely determined
        }
    }

    if (done) {
        #pragma unroll
        for (int j = 0; j < 16; ++j) mb[j] = (su[j] >= T) ? 1.0f : 0.0f;
        return;
    }

    const unsigned cnt_gt = count_ge(T + 1u);
    const unsigned need_eq = KKEEP - cnt_gt;

    unsigned local_eq = 0;
    #pragma unroll
    for (int j = 0; j < 16; ++j) local_eq += (su[j] == T) ? 1u : 0u;
    cnts[t] = local_eq;
    __syncthreads();
    unsigned prefix = 0;
    for (int p = 0; p < t; ++p) prefix += cnts[p];

    unsigned run = prefix;
    #pragma unroll
    for (int j = 0; j < 16; ++j) {
        bool sel;
        if (su[j] > T)       sel = true;
        else if (su[j] == T) { sel = (run < need_eq); ++run; }
        else                 sel = false;
        mb[j] = sel ? 1.0f : 0.0f;
    }
}

__global__ __launch_bounds__(256) void pool_kernel(
    const float* __restrict__ x, const float* __restrict__ M,
    float* __restrict__ out) {
    const int wave = threadIdx.x >> 6;
    const int lane = threadIdx.x & 63;
    const int u    = (blockIdx.x << 2) | wave;   // 0..4095 units of 4 rows
    const int inv  = 4095 - u;                   // reverse k1 read-time order
    const int cyk  = inv >> 9;                   // k1 chunk (outer in time), 0..7
    const int rem  = inv & 511;
    const int bk   = rem >> 3;                   // k1 batch (inner in time)
    const int cb   = rem & 7;                    // 4-channel group within chunk
    const int row0 = bk * CC + cyk * CCHUNK + cb * 4;
    const float* xr = x + (size_t)row0 * NN;
    const float* mr = M + (size_t)bk * NN;
    float a0 = 0.f, a1 = 0.f, a2 = 0.f, a3 = 0.f;
    #pragma unroll 4
    for (int j = 0; j < 16; ++j) {
        const int n = j * 256 + lane * 4;
        const float4 m  = *(const float4*)(mr + n);   // shared by 4 rows
        const float4 v0 = *(const float4*)(xr + n);
        const float4 v1 = *(const float4*)(xr + (size_t)NN + n);
        const float4 v2 = *(const float4*)(xr + (size_t)2 * NN + n);
        const float4 v3 = *(const float4*)(xr + (size_t)3 * NN + n);
        a0 += v0.x * m.x + v0.y * m.y + v0.z * m.z + v0.w * m.w;
        a1 += v1.x * m.x + v1.y * m.y + v1.z * m.z + v1.w * m.w;
        a2 += v2.x * m.x + v2.y * m.y + v2.z * m.z + v2.w * m.w;
        a3 += v3.x * m.x + v3.y * m.y + v3.z * m.z + v3.w * m.w;
    }
    #pragma unroll
    for (int off = 32; off; off >>= 1) {
        a0 += __shfl_down(a0, off, 64);
        a1 += __shfl_down(a1, off, 64);
        a2 += __shfl_down(a2, off, 64);
        a3 += __shfl_down(a3, off, 64);
    }
    if (lane == 0) {
        const float s = 1.0f / 2048.0f;
        *(float4*)(out + row0) = make_float4(a0 * s, a1 * s, a2 * s, a3 * s);
    }
}

extern "C" void kernel_launch(void* const* d_in, const int* in_sizes, int n_in,
                              void* d_out, int out_size, void* d_ws, size_t ws_size,
                              hipStream_t stream) {
    const float* x = (const float*)d_in[0];
    float* out = (float*)d_out;
    float* P = (float*)d_ws;
    float* M = P + (size_t)NCHUNK * BB * NN;

    // k1 launched 3x: pure function of x -> identical P bytes each time.
    // dur_us - 420.86 (R4 baseline) = 2*(k1 + ~3 us gap).
    score_partial_kernel<<<dim3(BB * 4, NCHUNK), 256, 0, stream>>>(x, P);
    score_partial_kernel<<<dim3(BB * 4, NCHUNK), 256, 0, stream>>>(x, P);
    score_partial_kernel<<<dim3(BB * 4, NCHUNK), 256, 0, stream>>>(x, P);
    select_kernel<<<BB, 256, 0, stream>>>(P, M);
    pool_kernel<<<(BB * CC) / 16, 256, 0, stream>>>(x, M, out);
}

// Round 7
// 446.185 us; speedup vs baseline: 1.2959x; 1.1701x over previous
//
#include <hip/hip_runtime.h>

// Problem constants (reference: x [64,256,64,64] fp32, keep_num=2048)
#define BB 64
#define CC 256
#define NN 4096          // 64*64 tokens
#define KKEEP 2048
#define NCHUNK 8         // channel chunks
#define CCHUNK 32        // channels per chunk (8 x 32 = 256)

// ---------------------------------------------------------------------------
// Ledger after R5/R6 measurement rounds (fill=160, residue=92.5 fixed):
//   k1 ~ 47 us (AT cold-HBM roofline, exonerated R6)
//   k3 ~ 48 us (L3-served, ~5.5 TB/s effective)
//   k2 + gap ~ 65 us  <-- unexplained 10x anomaly OR broken accounting.
// This round: REWRITTEN k2 (min/max common-prefix skip cuts ~13 of ~28
// count rounds) launched 3x to measure it directly, + k3 reverted to
// 1-row/wave (4x TLP on the L3-latency-bound path).
// ---------------------------------------------------------------------------

__global__ __launch_bounds__(256, 8) void score_partial_kernel(
    const float* __restrict__ x, float* __restrict__ P) {
    const int b  = blockIdx.x >> 2;
    const int ng = blockIdx.x & 3;
    const int cy = blockIdx.y;
    const int n0 = ng * 1024 + threadIdx.x * 4;
    const float* xb = x + (size_t)(b * CC + cy * CCHUNK) * NN + n0;
    float4 acc = make_float4(0.f, 0.f, 0.f, 0.f);
    #pragma unroll 8
    for (int c = 0; c < CCHUNK; ++c) {
        const float4 v = *(const float4*)(xb + (size_t)c * NN);
        acc.x += fabsf(v.x); acc.y += fabsf(v.y);
        acc.z += fabsf(v.z); acc.w += fabsf(v.w);
    }
    *(float4*)(P + (size_t)(cy * BB + b) * NN + n0) = acc;
}

// ---------------------------------------------------------------------------
// Kernel 2 (rewritten): per-batch top-k -> 0/1 mask.
// Scores >= 0 -> fp32 bits uint32-order-isomorphic.  New vs R4:
//  * block min AND max computed once; kth-largest lies in [mn,mx] so the
//    greedy bit-build starts at the first differing bit of mn^mx (common
//    prefix copied into T for free) -- data-typical skip: ~13 rounds.
//  * retained: 1-barrier double-buffered count rounds, free reject vs mx,
//    exact-count early exit, jax-compatible lowest-index tie-break.
// ---------------------------------------------------------------------------
__global__ __launch_bounds__(256) void select_kernel(
    const float* __restrict__ P, float* __restrict__ M) {
    const int b = blockIdx.x;
    const int t = threadIdx.x;
    __shared__ unsigned wred[2][4];
    __shared__ unsigned wmn[4], wmx[4];
    __shared__ unsigned cnts[256];

    const int base = t * 16;
    unsigned su[16];
    #pragma unroll
    for (int j = 0; j < 16; j += 4) {
        float4 s = make_float4(0.f, 0.f, 0.f, 0.f);
        #pragma unroll
        for (int cy = 0; cy < NCHUNK; ++cy) {
            const float4 a = *(const float4*)(P + (size_t)(cy * BB + b) * NN + base + j);
            s.x += a.x; s.y += a.y; s.z += a.z; s.w += a.w;
        }
        su[j + 0] = __float_as_uint(s.x);
        su[j + 1] = __float_as_uint(s.y);
        su[j + 2] = __float_as_uint(s.z);
        su[j + 3] = __float_as_uint(s.w);
    }

    int slot = 0;
    auto reduce_add = [&](unsigned v) -> unsigned {
        #pragma unroll
        for (int off = 32; off; off >>= 1) v += __shfl_down(v, off, 64);
        if ((t & 63) == 0) wred[slot][t >> 6] = v;
        __syncthreads();
        unsigned tot = wred[slot][0] + wred[slot][1] + wred[slot][2] + wred[slot][3];
        slot ^= 1;
        return tot;
    };
    auto count_ge = [&](unsigned thr) -> unsigned {
        unsigned c = 0;
        #pragma unroll
        for (int j = 0; j < 16; ++j) c += (su[j] >= thr) ? 1u : 0u;
        return reduce_add(c);
    };

    // block min AND max in one pass (independent shfl chains interleave)
    unsigned lmn = su[0], lmx = su[0];
    #pragma unroll
    for (int j = 1; j < 16; ++j) {
        lmn = (su[j] < lmn) ? su[j] : lmn;
        lmx = (su[j] > lmx) ? su[j] : lmx;
    }
    #pragma unroll
    for (int off = 32; off; off >>= 1) {
        const unsigned wn = __shfl_down(lmn, off, 64);
        const unsigned wx = __shfl_down(lmx, off, 64);
        lmn = (wn < lmn) ? wn : lmn;
        lmx = (wx > lmx) ? wx : lmx;
    }
    if ((t & 63) == 0) { wmn[t >> 6] = lmn; wmx[t >> 6] = lmx; }
    __syncthreads();
    unsigned mn = wmn[0], mx = wmx[0];
    #pragma unroll
    for (int w = 1; w < 4; ++w) {
        mn = (wmn[w] < mn) ? wmn[w] : mn;
        mx = (wmx[w] > mx) ? wmx[w] : mx;
    }

    float* mb = M + (size_t)b * NN + base;

    unsigned T;
    bool done = false;
    const unsigned diff = mn ^ mx;
    if (diff == 0) {
        T = mn;               // all scores equal -> tie path selects first K
    } else {
        const int hb = 31 - __clz(diff);   // first differing bit
        T = (hb >= 31) ? 0u : (mn & ~((1u << (hb + 1)) - 1u));  // common prefix
        for (int bit = hb; bit >= 0; --bit) {
            const unsigned cand = T | (1u << bit);
            if (cand > mx) continue;           // free reject
            const unsigned c = count_ge(cand);
            if (c >= KKEEP) {
                T = cand;
                if (c == KKEEP) { done = true; break; }
            }
        }
    }

    if (done) {
        #pragma unroll
        for (int j = 0; j < 16; ++j) mb[j] = (su[j] >= T) ? 1.0f : 0.0f;
        return;
    }

    // Tie path: exact collisions at the threshold; keep lowest indices first.
    const unsigned cnt_gt = count_ge(T + 1u);
    const unsigned need_eq = KKEEP - cnt_gt;

    unsigned local_eq = 0;
    #pragma unroll
    for (int j = 0; j < 16; ++j) local_eq += (su[j] == T) ? 1u : 0u;
    cnts[t] = local_eq;
    __syncthreads();
    unsigned prefix = 0;
    for (int p = 0; p < t; ++p) prefix += cnts[p];

    unsigned run = prefix;
    #pragma unroll
    for (int j = 0; j < 16; ++j) {
        bool sel;
        if (su[j] > T)       sel = true;
        else if (su[j] == T) { sel = (run < need_eq); ++run; }
        else                 sel = false;
        mb[j] = sel ? 1.0f : 0.0f;
    }
}

// ---------------------------------------------------------------------------
// Kernel 3 (reverted to 1-row/wave): out[b][c] = (1/2048)*sum_n M[b][n]*x[b,c,n]
// 4096 blocks x 4 waves = 16384 waves, one 16-KB row each -> 4x the TLP of
// the 4-row/wave form (R5 measured that at ~48 us ~ 5.5 TB/s: latency-bound,
// not BW-bound, so more waves in flight is the lever).  Row walk stays in
// REVERSE k1 read-time order (cy desc, b desc, c desc) -- L3-LIFO reuse
// proven in R3 (one-pass FETCH for the whole two-pass algorithm).
// ---------------------------------------------------------------------------
__global__ __launch_bounds__(256) void pool_kernel(
    const float* __restrict__ x, const float* __restrict__ M,
    float* __restrict__ out) {
    const int wave = threadIdx.x >> 6;
    const int lane = threadIdx.x & 63;
    const int w    = (blockIdx.x << 2) | wave;   // 0..16383 row units
    const int inv  = 16383 - w;                  // reverse k1 read-time order
    const int cyk  = inv >> 11;                  // chunk (outer in k1 time)
    const int rem  = inv & 2047;
    const int bk   = rem >> 5;                   // batch
    const int cc   = rem & 31;                   // channel within chunk
    const int row  = bk * CC + cyk * CCHUNK + cc;
    const float* xr = x + (size_t)row * NN;
    const float* mr = M + (size_t)bk * NN;
    float acc = 0.f;
    #pragma unroll
    for (int j = 0; j < 16; ++j) {
        const int n = j * 256 + lane * 4;
        const float4 v = *(const float4*)(xr + n);
        const float4 m = *(const float4*)(mr + n);
        acc += v.x * m.x + v.y * m.y + v.z * m.z + v.w * m.w;
    }
    #pragma unroll
    for (int off = 32; off; off >>= 1) acc += __shfl_down(acc, off, 64);
    if (lane == 0) out[row] = acc * (1.0f / 2048.0f);
}

extern "C" void kernel_launch(void* const* d_in, const int* in_sizes, int n_in,
                              void* d_out, int out_size, void* d_ws, size_t ws_size,
                              hipStream_t stream) {
    const float* x = (const float*)d_in[0];
    float* out = (float*)d_out;
    float* P = (float*)d_ws;
    float* M = P + (size_t)NCHUNK * BB * NN;

    score_partial_kernel<<<dim3(BB * 4, NCHUNK), 256, 0, stream>>>(x, P);
    // NEW k2 launched 3x (pure function of P -> identical M bytes):
    // dur readout bands: ~360-390 anomaly-fixed / ~420-445 accounting-wrong /
    // ~500-540 k2-slow-in-any-form.
    select_kernel<<<BB, 256, 0, stream>>>(P, M);
    select_kernel<<<BB, 256, 0, stream>>>(P, M);
    select_kernel<<<BB, 256, 0, stream>>>(P, M);
    pool_kernel<<<BB * CC / 4, 256, 0, stream>>>(x, M, out);
}

// Round 8
// 415.198 us; speedup vs baseline: 1.3926x; 1.0746x over previous
//
#include <hip/hip_runtime.h>

// Problem constants (reference: x [64,256,64,64] fp32, keep_num=2048)
#define BB 64
#define CC 256
#define NN 4096          // 64*64 tokens
#define KKEEP 2048
#define NCHUNK 8         // channel chunks
#define CCHUNK 32        // channels per chunk (8 x 32 = 256)

// ---------------------------------------------------------------------------
// Ledger (R3-R7 measurement rounds; fill=160, residue=92.5):
//   k1 ~ 47 us  -- measured AT cold-HBM roofline (R6), frozen.
//   k3 ~ 50 us  -- same at 4-row/wave AND 1-row/wave -> L3-BW ceiling
//                  (~5.4 TB/s effective), frozen.
//   k2: cost scales with barrier-separated count rounds (~2 us/round,
//       A/B-confirmed R4 vs R7: ~25 rounds=65us, ~12 rounds=31us).
// This round: radix-select k2 (3 x 8-bit histogram passes instead of
// ~12-20 bit rounds), need_eq derived from the radix invariant for free.
// ---------------------------------------------------------------------------

__global__ __launch_bounds__(256, 8) void score_partial_kernel(
    const float* __restrict__ x, float* __restrict__ P) {
    const int b  = blockIdx.x >> 2;
    const int ng = blockIdx.x & 3;
    const int cy = blockIdx.y;
    const int n0 = ng * 1024 + threadIdx.x * 4;
    const float* xb = x + (size_t)(b * CC + cy * CCHUNK) * NN + n0;
    float4 acc = make_float4(0.f, 0.f, 0.f, 0.f);
    #pragma unroll 8
    for (int c = 0; c < CCHUNK; ++c) {
        const float4 v = *(const float4*)(xb + (size_t)c * NN);
        acc.x += fabsf(v.x); acc.y += fabsf(v.y);
        acc.z += fabsf(v.z); acc.w += fabsf(v.w);
    }
    *(float4*)(P + (size_t)(cy * BB + b) * NN + n0) = acc;
}

// ---------------------------------------------------------------------------
// Kernel 2 (radix-select): per-batch top-k -> 0/1 mask.
// Scores >= 0 -> fp32 bits uint32-order-isomorphic (sign bit always 0).
// 1) block min/max (1 barrier) -> common prefix above hb = first differing
//    bit of mn^mx is skipped entirely.
// 2) 8-bit-digit radix passes over bits [hb..0] (<=3 passes for this data,
//    <=4 ever).  Per pass: zero bins, LDS-atomic histogram of the digit
//    (only values matching the prefix so far), wave-level suffix scan via
//    masked shfl_down + cross-wave totals, pick g* = max digit with
//    suffix(g*) >= K, update prefix and K -= suffix(g*+1).
// 3) Invariant: after the last pass T = prefix = kth-largest bit pattern and
//    K = need_eq = #threshold-equal tokens to keep.  count(v>T) = KKEEP - K,
//    so NO extra count round.  Mask write = R0-harness-verified tie path
//    (lowest token index first, matching jax.lax.top_k + sort).
// ---------------------------------------------------------------------------
__global__ __launch_bounds__(256) void select_kernel(
    const float* __restrict__ P, float* __restrict__ M) {
    const int b = blockIdx.x;
    const int t = threadIdx.x;
    __shared__ unsigned cnt256[257];   // bins / suffix sums; [256] stays 0
    __shared__ unsigned wtot[4];
    __shared__ unsigned wmn[4], wmx[4];
    __shared__ unsigned bg, bK;

    const int base = t * 16;
    unsigned su[16];
    #pragma unroll
    for (int j = 0; j < 16; j += 4) {
        float4 s = make_float4(0.f, 0.f, 0.f, 0.f);
        #pragma unroll
        for (int cy = 0; cy < NCHUNK; ++cy) {
            const float4 a = *(const float4*)(P + (size_t)(cy * BB + b) * NN + base + j);
            s.x += a.x; s.y += a.y; s.z += a.z; s.w += a.w;
        }
        su[j + 0] = __float_as_uint(s.x);
        su[j + 1] = __float_as_uint(s.y);
        su[j + 2] = __float_as_uint(s.z);
        su[j + 3] = __float_as_uint(s.w);
    }

    // block min AND max (one barrier)
    unsigned lmn = su[0], lmx = su[0];
    #pragma unroll
    for (int j = 1; j < 16; ++j) {
        lmn = (su[j] < lmn) ? su[j] : lmn;
        lmx = (su[j] > lmx) ? su[j] : lmx;
    }
    #pragma unroll
    for (int off = 32; off; off >>= 1) {
        const unsigned wn = __shfl_down(lmn, off, 64);
        const unsigned wx = __shfl_down(lmx, off, 64);
        lmn = (wn < lmn) ? wn : lmn;
        lmx = (wx > lmx) ? wx : lmx;
    }
    if ((t & 63) == 0) { wmn[t >> 6] = lmn; wmx[t >> 6] = lmx; }
    __syncthreads();
    unsigned mn = wmn[0], mx = wmx[0];
    #pragma unroll
    for (int w = 1; w < 4; ++w) {
        mn = (wmn[w] < mn) ? wmn[w] : mn;
        mx = (wmx[w] > mx) ? wmx[w] : mx;
    }

    unsigned T, need_eq;
    const unsigned diff = mn ^ mx;
    if (diff == 0) {
        T = mn; need_eq = KKEEP;       // all scores equal -> keep first K
    } else {
        const int hb = 31 - __clz(diff);           // <= 30 (sign bit is 0)
        unsigned prefix = mn & ~((1u << (hb + 1)) - 1u);  // common high bits
        int s = hb - 7; if (s < 0) s = 0;
        int prev_s = 31;               // pass-1 check (su>>31==0) is always true
        unsigned K = KKEEP;
        const int lane = t & 63, wv = t >> 6;
        for (;;) {
            cnt256[t] = 0;
            if (t == 0) cnt256[256] = 0;
            __syncthreads();
            const unsigned pchk = prefix >> prev_s;
            #pragma unroll
            for (int j = 0; j < 16; ++j) {
                if ((su[j] >> prev_s) == pchk)
                    atomicAdd(&cnt256[(su[j] >> s) & 255u], 1u);
            }
            __syncthreads();
            // suffix sum within each wave's 64-bin segment (masked shfl_down)
            unsigned v = cnt256[t];
            #pragma unroll
            for (int off = 1; off < 64; off <<= 1) {
                const unsigned tmp = __shfl_down(v, off, 64);
                if (lane + off < 64) v += tmp;
            }
            if (lane == 0) wtot[wv] = v;   // segment total
            __syncthreads();
            unsigned S = v;
            #pragma unroll
            for (int w2 = 0; w2 < 4; ++w2) if (w2 > wv) S += wtot[w2];
            cnt256[t] = S;                 // S = count of digit >= t
            __syncthreads();
            const unsigned Sp1 = cnt256[t + 1];
            if (S >= K && Sp1 < K) { bg = (unsigned)t; bK = K - Sp1; }  // unique t
            __syncthreads();
            prefix |= bg << s;
            K = bK;
            if (s == 0) break;
            prev_s = s;
            s -= 8; if (s < 0) s = 0;
        }
        T = prefix; need_eq = K;
    }

    // Mask write: R0-verified tie path (always).  sel = (>T) or (==T and
    // token-order rank < need_eq).
    float* mb = M + (size_t)b * NN + base;
    unsigned local_eq = 0;
    #pragma unroll
    for (int j = 0; j < 16; ++j) local_eq += (su[j] == T) ? 1u : 0u;
    cnt256[t] = local_eq;                  // safe: last cnt256 reads pre-barrier
    __syncthreads();
    unsigned prefix_eq = 0;
    for (int p = 0; p < t; ++p) prefix_eq += cnt256[p];

    unsigned run = prefix_eq;
    #pragma unroll
    for (int j = 0; j < 16; ++j) {
        bool sel;
        if (su[j] > T)       sel = true;
        else if (su[j] == T) { sel = (run < need_eq); ++run; }
        else                 sel = false;
        mb[j] = sel ? 1.0f : 0.0f;
    }
}

// ---------------------------------------------------------------------------
// Kernel 3 (frozen): out[b][c] = (1/2048)*sum_n M[b][n]*x[b,c,n]
// 1-row/wave, reverse k1 read-time order (L3-LIFO reuse, proven R3).
// ~50 us at both 1-row and 4-row granularity -> L3-BW ceiling.
// ---------------------------------------------------------------------------
__global__ __launch_bounds__(256) void pool_kernel(
    const float* __restrict__ x, const float* __restrict__ M,
    float* __restrict__ out) {
    const int wave = threadIdx.x >> 6;
    const int lane = threadIdx.x & 63;
    const int w    = (blockIdx.x << 2) | wave;   // 0..16383 row units
    const int inv  = 16383 - w;                  // reverse k1 read-time order
    const int cyk  = inv >> 11;
    const int rem  = inv & 2047;
    const int bk   = rem >> 5;
    const int cc   = rem & 31;
    const int row  = bk * CC + cyk * CCHUNK + cc;
    const float* xr = x + (size_t)row * NN;
    const float* mr = M + (size_t)bk * NN;
    float acc = 0.f;
    #pragma unroll
    for (int j = 0; j < 16; ++j) {
        const int n = j * 256 + lane * 4;
        const float4 v = *(const float4*)(xr + n);
        const float4 m = *(const float4*)(mr + n);
        acc += v.x * m.x + v.y * m.y + v.z * m.z + v.w * m.w;
    }
    #pragma unroll
    for (int off = 32; off; off >>= 1) acc += __shfl_down(acc, off, 64);
    if (lane == 0) out[row] = acc * (1.0f / 2048.0f);
}

extern "C" void kernel_launch(void* const* d_in, const int* in_sizes, int n_in,
                              void* d_out, int out_size, void* d_ws, size_t ws_size,
                              hipStream_t stream) {
    const float* x = (const float*)d_in[0];
    float* out = (float*)d_out;
    float* P = (float*)d_ws;
    float* M = P + (size_t)NCHUNK * BB * NN;

    score_partial_kernel<<<dim3(BB * 4, NCHUNK), 256, 0, stream>>>(x, P);
    select_kernel<<<BB, 256, 0, stream>>>(P, M);
    pool_kernel<<<BB * CC / 4, 256, 0, stream>>>(x, M, out);
}